// Round 3
// baseline (478.534 us; speedup 1.0000x reference)
//
#include <hip/hip_runtime.h>
#include <hip/hip_bf16.h>
#include <cstdint>
#include <cstddef>

#define K_DIM 4096

typedef __bf16 bf16x8 __attribute__((ext_vector_type(8)));
typedef float  f32x4  __attribute__((ext_vector_type(4)));
typedef unsigned short ushort8 __attribute__((ext_vector_type(8)));

struct KronPtrs { const float* a[8]; const float* b[8]; };

// ---------------------------------------------------------------------------
// Fused prologue (unchanged — write-bound, ~22 µs).
// ---------------------------------------------------------------------------
__global__ __launch_bounds__(256) void prologue_kernel(
        KronPtrs P,
        const float* __restrict__ x,
        __hip_bfloat16* __restrict__ Wb,
        __hip_bfloat16* __restrict__ Xb)
{
    __shared__ __align__(16) float sa[1080];
    __shared__ __align__(16) float sb[1080];

    const int tid = threadIdx.x;

    if (blockIdx.x < 8192) {
        const size_t t = (size_t)blockIdx.x * 256 + tid;
        const size_t o = t * 8;
        const float4 v0 = *(const float4*)(x + o);
        const float4 v1 = *(const float4*)(x + o + 4);
        union { __hip_bfloat16 h[8]; ushort8 v; } u;
        u.h[0] = __float2bfloat16(v0.x);
        u.h[1] = __float2bfloat16(v0.y);
        u.h[2] = __float2bfloat16(v0.z);
        u.h[3] = __float2bfloat16(v0.w);
        u.h[4] = __float2bfloat16(v1.x);
        u.h[5] = __float2bfloat16(v1.y);
        u.h[6] = __float2bfloat16(v1.z);
        u.h[7] = __float2bfloat16(v1.w);
        *(ushort8*)(void*)(Xb + o) = u.v;
        return;
    }

    const int row = blockIdx.x - 8192;

#define STAGE(IDX, MA, LB, OA, OB)                                             \
    {                                                                          \
        const int mb_ = 1 << (LB);                                             \
        const float* ap = P.a[IDX] + (size_t)(row >> (LB)) * (MA);             \
        const float* bp = P.b[IDX] + (size_t)(row & (mb_ - 1)) * mb_;          \
        for (int i = tid; i < (MA); i += 256) sa[(OA) + i] = ap[i];            \
        for (int i = tid; i < mb_;  i += 256) sb[(OB) + i] = bp[i];            \
    }

    STAGE(0,  64, 6,   0,    0)
    STAGE(1,  64, 6,  64,   64)
    STAGE(2,  32, 7, 128,  128)
    STAGE(3, 128, 5, 160,  256)
    STAGE(4,  16, 8, 288,  288)
    STAGE(5, 256, 4, 304,  544)
    STAGE(6,   8, 9, 560,  560)
    STAGE(7, 512, 3, 568, 1072)
#undef STAGE

    __syncthreads();

    const float s = 0.17677669529663687f;  // 1 / (2*sqrt(8))
    const int q0 = tid << 4;

#pragma unroll
    for (int g = 0; g < 2; ++g) {
        const int q8 = q0 + (g << 3);
        float acc[8] = {0.f,0.f,0.f,0.f,0.f,0.f,0.f,0.f};

#define KTERM(LB, OA, OB)                                                      \
    {                                                                          \
        const int mb_   = 1 << (LB);                                           \
        const float av  = sa[(OA) + (q8 >> (LB))];                             \
        const float* bp = sb + (OB) + (q8 & (mb_ - 1));                        \
        const float4 x0 = *(const float4*)(bp);                                \
        const float4 x1 = *(const float4*)(bp + 4);                            \
        acc[0] += av * x0.x; acc[1] += av * x0.y;                              \
        acc[2] += av * x0.z; acc[3] += av * x0.w;                              \
        acc[4] += av * x1.x; acc[5] += av * x1.y;                              \
        acc[6] += av * x1.z; acc[7] += av * x1.w;                              \
    }

        KTERM(6,   0,    0)
        KTERM(6,  64,   64)
        KTERM(7, 128,  128)
        KTERM(5, 160,  256)
        KTERM(8, 288,  288)
        KTERM(4, 304,  544)
        KTERM(9, 560,  560)
        KTERM(3, 568, 1072)
#undef KTERM

        union { __hip_bfloat16 h[8]; ushort8 v; } u;
#pragma unroll
        for (int i = 0; i < 8; ++i) u.h[i] = __float2bfloat16(acc[i] * s);
        *(ushort8*)(void*)(Wb + (size_t)row * K_DIM + q8) = u.v;
    }
}

// ---------------------------------------------------------------------------
// GEMM R7 = R6's read-ahead pipeline with the cross-wave vmcnt race fixed.
// THE R6 BUG: vmcnt is PER-WAVE. R6 issued the next-tile read-ahead (NRD)
// between this wave's vmcnt(6) and the barrier — other waves' staging loads
// for that tile were not yet proven landed. Invariant restored here:
// every wave drains vmcnt -> BARRIER -> only then any wave reads that tile.
// So the counted vmcnt now sits at PH2-END (before the ph2 trailing barrier),
// and the prologue barrier comes BEFORE the initial read-ahead.
//
// Per tile t (buffer p), loop-carried: af[0]/bf[0] hold this tile's A0/B0
// frags (read in prev tile's ph3, after the vm-drain barrier):
//   ph0: read B1(p)[4];                    lgkm(4);  MMA(0,0); bar
//   ph1: read A1(p)[8]; stageA0(t+2);      lgkm(8);  MMA(0,1); bar
//   ph2: stageB0,B1(t+2);                  lgkm(0);  MMA(1,0); vmcnt(6); bar
//   ph3: read A0,B0 of t+1 [12]; stageA1(t+2); lgkm(12); MMA(1,1); bar
// vmcnt ledger (per wave, oldest->newest at ph2-end): tile t+1's 8, then
// t+2's A0(2)+B0B1(4)=6  ->  vmcnt(6) == tile t+1 fully landed. Barrier
// makes that true for ALL waves before ph3's reads touch t+1.     WAR: each
// region's last reads complete (counted lgkm) >=1 barrier before overwrite.
// Stage swizzle unchanged (measured 0 bank conflicts).
// ---------------------------------------------------------------------------
__device__ __forceinline__ void gload_lds16(const void* g, void* l)
{
    __builtin_amdgcn_global_load_lds((const __attribute__((address_space(1))) void*)g,
                                     (__attribute__((address_space(3))) void*)l,
                                     16, 0, 0);
}

__global__ __launch_bounds__(512) void gemm_kernel(
        const __hip_bfloat16* __restrict__ Wb,
        const __hip_bfloat16* __restrict__ Xb,
        const float* __restrict__ bias,
        float* __restrict__ C)
{
    // [buf*2 + half][128 rows * 64 cols]
    __shared__ __align__(16) __hip_bfloat16 lsA[4][8192];   // 64 KiB
    __shared__ __align__(16) __hip_bfloat16 lsB[4][8192];   // 64 KiB

    const int tid  = threadIdx.x;
    const int lane = tid & 63;
    const int wid  = tid >> 6;    // 0..7
    const int wr   = wid >> 2;    // 0..1 (M)
    const int wc   = wid & 3;     // 0..3 (N)

    // XCD-aware bijective swizzle of the 256-block grid (16x16 tiles).
    const int bid = blockIdx.x;
    const int lin = (bid & 7) * 32 + (bid >> 3);
    const int bm  = (lin >> 4) << 8;
    const int bn  = (lin & 15) << 8;

    // --- staging source pointers (pre-swizzled global addresses) ---
    const int sr = lane >> 3;            // row within 8-row chunk
    const int lc = (lane & 7) ^ sr;      // logical 16B chunk to fetch
    const __hip_bfloat16* gA[2][2];
    const __hip_bfloat16* gB[2][2];
#pragma unroll
    for (int h = 0; h < 2; ++h)
#pragma unroll
        for (int r = 0; r < 2; ++r) {
            const int rowo = h * 128 + (wid + 8 * r) * 8 + sr;
            gA[h][r] = Wb + (size_t)(bm + rowo) * K_DIM + lc * 8;
            gB[h][r] = Xb + (size_t)(bn + rowo) * K_DIM + lc * 8;
        }

    // --- accumulators: per-wave 128x64 output, quadrants [m][n], frags [mi][ni]
    f32x4 acc[2][2][4][2];
#pragma unroll
    for (int m = 0; m < 2; ++m)
#pragma unroll
        for (int n = 0; n < 2; ++n)
#pragma unroll
            for (int mi = 0; mi < 4; ++mi)
#pragma unroll
                for (int ni = 0; ni < 2; ++ni) acc[m][n][mi][ni] = (f32x4)(0.0f);

    bf16x8 af[2][2][4];   // A frags [m-half][kk][mi]  (ping-pong by m)
    bf16x8 bf[2][2][2];   // B frags [n-half][kk][ni]

    const int fr = lane & 15;   // frag row
    const int fq = lane >> 4;   // quad
    const int fx = fr & 7;      // read-side swizzle xor

    const int e0 = (fq ^ fx) << 3;                      // kk=0 chunk, elements
    const int dK = (fx & 4) ? -32 : 32;                 // kk=1 chunk delta (elems)
    const __hip_bfloat16* aPtr[2];
    const __hip_bfloat16* bPtr[2];
    aPtr[0] = &lsA[0][0] + ((wr << 6) + fr) * 64 + e0;
    aPtr[1] = &lsA[1][0] + ((wr << 6) + fr) * 64 + e0;
    bPtr[0] = &lsB[0][0] + ((wc << 5) + fr) * 64 + e0;
    bPtr[1] = &lsB[1][0] + ((wc << 5) + fr) * 64 + e0;

#define STAGE_A(h, p) do {                                                     \
    gload_lds16(gA[h][0], &lsA[(p)*2 + (h)][wid << 9]);       gA[h][0] += 64;  \
    gload_lds16(gA[h][1], &lsA[(p)*2 + (h)][(wid + 8) << 9]); gA[h][1] += 64;  \
} while (0)

#define STAGE_B(h, p) do {                                                     \
    gload_lds16(gB[h][0], &lsB[(p)*2 + (h)][wid << 9]);       gB[h][0] += 64;  \
    gload_lds16(gB[h][1], &lsB[(p)*2 + (h)][(wid + 8) << 9]); gB[h][1] += 64;  \
} while (0)

// 8 ds_read_b128: A-half h of buffer p -> af[h]
#define LOAD_AH(p, h) do {                                                     \
    const __hip_bfloat16* _pa = aPtr[h] + (p) * 16384;                         \
    af[h][0][0] = *(const bf16x8*)(const void*)(_pa);                          \
    af[h][0][1] = *(const bf16x8*)(const void*)(_pa + 1024);                   \
    af[h][0][2] = *(const bf16x8*)(const void*)(_pa + 2048);                   \
    af[h][0][3] = *(const bf16x8*)(const void*)(_pa + 3072);                   \
    af[h][1][0] = *(const bf16x8*)(const void*)(_pa + dK);                     \
    af[h][1][1] = *(const bf16x8*)(const void*)(_pa + dK + 1024);              \
    af[h][1][2] = *(const bf16x8*)(const void*)(_pa + dK + 2048);              \
    af[h][1][3] = *(const bf16x8*)(const void*)(_pa + dK + 3072);              \
} while (0)

// 4 ds_read_b128: B-half h of buffer p -> bf[h]
#define LOAD_BH(p, h) do {                                                     \
    const __hip_bfloat16* _pb = bPtr[h] + (p) * 16384;                         \
    bf[h][0][0] = *(const bf16x8*)(const void*)(_pb);                          \
    bf[h][0][1] = *(const bf16x8*)(const void*)(_pb + 1024);                   \
    bf[h][1][0] = *(const bf16x8*)(const void*)(_pb + dK);                     \
    bf[h][1][1] = *(const bf16x8*)(const void*)(_pb + dK + 1024);              \
} while (0)

#define MMA(m, n) do {                                                         \
    __builtin_amdgcn_s_setprio(1);                                             \
    _Pragma("unroll") for (int kk = 0; kk < 2; ++kk)                           \
    _Pragma("unroll") for (int mi = 0; mi < 4; ++mi)                           \
    _Pragma("unroll") for (int ni = 0; ni < 2; ++ni)                           \
        acc[m][n][mi][ni] = __builtin_amdgcn_mfma_f32_16x16x32_bf16(           \
            af[m][kk][mi], bf[n][kk][ni], acc[m][n][mi][ni], 0, 0, 0);         \
    __builtin_amdgcn_s_setprio(0);                                             \
} while (0)

#define BAR()        __builtin_amdgcn_s_barrier()
#define WAIT_LGKM(N) asm volatile("s_waitcnt lgkmcnt(" #N ")" ::: "memory")
#define WAIT_VM(N)   asm volatile("s_waitcnt vmcnt(" #N ")" ::: "memory")

    // STG: 1 = stage tile t+2 into buffer p. VM: counted vmcnt at PH2-END
    // (drain-then-barrier-then-read invariant). NRD: read-ahead of next
    // tile's A0,B0 (after the vm-drain barrier). LG3: lgkm count at ph3.
#define TILE(p, STG, VM, NRD, LG3) do {                                        \
    /* ph0 */                                                                  \
    LOAD_BH(p, 1);                                                             \
    WAIT_LGKM(4); MMA(0, 0); BAR();                                            \
    /* ph1 */                                                                  \
    LOAD_AH(p, 1);                                                             \
    if (STG) STAGE_A(0, p);                                                    \
    WAIT_LGKM(8); MMA(0, 1); BAR();                                            \
    /* ph2 */                                                                  \
    if (STG) { STAGE_B(0, p); STAGE_B(1, p); }                                 \
    WAIT_LGKM(0); MMA(1, 0);                                                   \
    VM;                                   /* drain BEFORE the barrier */       \
    BAR();                                                                     \
    /* ph3 */                                                                  \
    NRD;                                  /* safe: all waves drained */        \
    if (STG) STAGE_A(1, p);                                                    \
    LG3; MMA(1, 1); BAR();                                                     \
} while (0)

#define NRD0 do { LOAD_AH(1, 0); LOAD_BH(1, 0); } while (0)   /* next = buf1 */
#define NRD1 do { LOAD_AH(0, 0); LOAD_BH(0, 0); } while (0)   /* next = buf0 */

    // Prologue: stage tiles 0 and 1 fully; drain tile0 on EVERY wave, then
    // barrier, THEN the initial read-ahead of tile0's A0,B0 (race-free).
    STAGE_A(0, 0); STAGE_B(0, 0); STAGE_B(1, 0); STAGE_A(1, 0);
    STAGE_A(0, 1); STAGE_B(0, 1); STAGE_B(1, 1); STAGE_A(1, 1);
    WAIT_VM(8);
    BAR();
    LOAD_AH(0, 0); LOAD_BH(0, 0);

    // Main loop: tiles 0..61 (31 iterations x 2 tiles, steady vmcnt(6)).
    for (int it = 0; it < 31; ++it) {
        TILE(0, 1, WAIT_VM(6), NRD0, WAIT_LGKM(12));
        TILE(1, 1, WAIT_VM(6), NRD1, WAIT_LGKM(12));
    }
    // Tile 62: no staging; vmcnt(0) at ph2-end drains tile 63 before its
    // read-ahead.
    TILE(0, 0, WAIT_VM(0), NRD0, WAIT_LGKM(12));
    // Tile 63: pure compute, no read-ahead.
    TILE(1, 0, (void)0, (void)0, WAIT_LGKM(0));

#undef NRD1
#undef NRD0
#undef TILE
#undef WAIT_VM
#undef WAIT_LGKM
#undef BAR
#undef MMA
#undef LOAD_BH
#undef LOAD_AH
#undef STAGE_B
#undef STAGE_A

    // Epilogue: C/D layout col = lane&15, row = (lane>>4)*4 + reg.
#pragma unroll
    for (int n = 0; n < 2; ++n)
#pragma unroll
        for (int ni = 0; ni < 2; ++ni) {
            const int col = bn + n * 128 + (wc << 5) + (ni << 4) + fr;
            const float bv = bias[col];
#pragma unroll
            for (int m = 0; m < 2; ++m)
#pragma unroll
                for (int mi = 0; mi < 4; ++mi) {
                    const int r0 = bm + m * 128 + (wr << 6) + (mi << 4) + (fq << 2);
#pragma unroll
                    for (int i = 0; i < 4; ++i)
                        C[(size_t)(r0 + i) * K_DIM + col] = acc[m][n][mi][ni][i] + bv;
                }
        }
}

// ---------------------------------------------------------------------------
extern "C" void kernel_launch(void* const* d_in, const int* in_sizes, int n_in,
                              void* d_out, int out_size, void* d_ws, size_t ws_size,
                              hipStream_t stream)
{
    (void)in_sizes; (void)n_in; (void)out_size; (void)ws_size;

    const float* x    = (const float*)d_in[0];
    KronPtrs P;
    for (int i = 0; i < 8; ++i) {
        P.a[i] = (const float*)d_in[1 + i];
        P.b[i] = (const float*)d_in[9 + i];
    }
    const float* bias = (const float*)d_in[17];

    __hip_bfloat16* Wb = (__hip_bfloat16*)d_ws;                               // 32 MiB
    __hip_bfloat16* Xb = (__hip_bfloat16*)((char*)d_ws +
                          (size_t)K_DIM * K_DIM * sizeof(__hip_bfloat16));    // 32 MiB
    float* y = (float*)d_out;

    prologue_kernel<<<12288, 256, 0, stream>>>(P, x, Wb, Xb);

    gemm_kernel<<<256, 512, 0, stream>>>(Wb, Xb, bias, y);
}

// Round 4
// 264.520 us; speedup vs baseline: 1.8091x; 1.8091x over previous
//
#include <hip/hip_runtime.h>
#include <hip/hip_bf16.h>
#include <cstdint>
#include <cstddef>

#define K_DIM 4096

typedef __bf16 bf16x8 __attribute__((ext_vector_type(8)));
typedef float  f32x4  __attribute__((ext_vector_type(4)));
typedef unsigned short ushort8 __attribute__((ext_vector_type(8)));

struct KronPtrs { const float* a[8]; const float* b[8]; };

// ---------------------------------------------------------------------------
// Fused prologue (unchanged).
// ---------------------------------------------------------------------------
__global__ __launch_bounds__(256) void prologue_kernel(
        KronPtrs P,
        const float* __restrict__ x,
        __hip_bfloat16* __restrict__ Wb,
        __hip_bfloat16* __restrict__ Xb)
{
    __shared__ __align__(16) float sa[1080];
    __shared__ __align__(16) float sb[1080];

    const int tid = threadIdx.x;

    if (blockIdx.x < 8192) {
        const size_t t = (size_t)blockIdx.x * 256 + tid;
        const size_t o = t * 8;
        const float4 v0 = *(const float4*)(x + o);
        const float4 v1 = *(const float4*)(x + o + 4);
        union { __hip_bfloat16 h[8]; ushort8 v; } u;
        u.h[0] = __float2bfloat16(v0.x);
        u.h[1] = __float2bfloat16(v0.y);
        u.h[2] = __float2bfloat16(v0.z);
        u.h[3] = __float2bfloat16(v0.w);
        u.h[4] = __float2bfloat16(v1.x);
        u.h[5] = __float2bfloat16(v1.y);
        u.h[6] = __float2bfloat16(v1.z);
        u.h[7] = __float2bfloat16(v1.w);
        *(ushort8*)(void*)(Xb + o) = u.v;
        return;
    }

    const int row = blockIdx.x - 8192;

#define STAGE(IDX, MA, LB, OA, OB)                                             \
    {                                                                          \
        const int mb_ = 1 << (LB);                                             \
        const float* ap = P.a[IDX] + (size_t)(row >> (LB)) * (MA);             \
        const float* bp = P.b[IDX] + (size_t)(row & (mb_ - 1)) * mb_;          \
        for (int i = tid; i < (MA); i += 256) sa[(OA) + i] = ap[i];            \
        for (int i = tid; i < mb_;  i += 256) sb[(OB) + i] = bp[i];            \
    }

    STAGE(0,  64, 6,   0,    0)
    STAGE(1,  64, 6,  64,   64)
    STAGE(2,  32, 7, 128,  128)
    STAGE(3, 128, 5, 160,  256)
    STAGE(4,  16, 8, 288,  288)
    STAGE(5, 256, 4, 304,  544)
    STAGE(6,   8, 9, 560,  560)
    STAGE(7, 512, 3, 568, 1072)
#undef STAGE

    __syncthreads();

    const float s = 0.17677669529663687f;  // 1 / (2*sqrt(8))
    const int q0 = tid << 4;

#pragma unroll
    for (int g = 0; g < 2; ++g) {
        const int q8 = q0 + (g << 3);
        float acc[8] = {0.f,0.f,0.f,0.f,0.f,0.f,0.f,0.f};

#define KTERM(LB, OA, OB)                                                      \
    {                                                                          \
        const int mb_   = 1 << (LB);                                           \
        const float av  = sa[(OA) + (q8 >> (LB))];                             \
        const float* bp = sb + (OB) + (q8 & (mb_ - 1));                        \
        const float4 x0 = *(const float4*)(bp);                                \
        const float4 x1 = *(const float4*)(bp + 4);                            \
        acc[0] += av * x0.x; acc[1] += av * x0.y;                              \
        acc[2] += av * x0.z; acc[3] += av * x0.w;                              \
        acc[4] += av * x1.x; acc[5] += av * x1.y;                              \
        acc[6] += av * x1.z; acc[7] += av * x1.w;                              \
    }

        KTERM(6,   0,    0)
        KTERM(6,  64,   64)
        KTERM(7, 128,  128)
        KTERM(5, 160,  256)
        KTERM(8, 288,  288)
        KTERM(4, 304,  544)
        KTERM(9, 560,  560)
        KTERM(3, 568, 1072)
#undef KTERM

        union { __hip_bfloat16 h[8]; ushort8 v; } u;
#pragma unroll
        for (int i = 0; i < 8; ++i) u.h[i] = __float2bfloat16(acc[i] * s);
        *(ushort8*)(void*)(Wb + (size_t)row * K_DIM + q8) = u.v;
    }
}

// ---------------------------------------------------------------------------
// GEMM R8 = R7's (proven-correct) read-ahead schedule + scalarized staging
// addresses. R7 spilled: 96 frag VGPR + 32 VGPR of persistent staging
// pointers > the 128-VGPR budget (acc holds the other 128 as AGPR at
// 2 waves/SIMD). Counter evidence: WRITE_SIZE 67->434 MB = scratch.
// Fix: all 16 staging pointers replaced by scalar bases (readfirstlane'd
// wave id) + ONE shared per-lane swizzle offset VGPR + loop-carried scalar
// kst. Addresses bit-identical to R7. Schedule, swizzle, lgkm/vmcnt ledger
// unchanged from R7 (see R7 comment for the race-freedom derivation).
// ---------------------------------------------------------------------------
__device__ __forceinline__ void gload_lds16(const void* g, void* l)
{
    __builtin_amdgcn_global_load_lds((const __attribute__((address_space(1))) void*)g,
                                     (__attribute__((address_space(3))) void*)l,
                                     16, 0, 0);
}

__global__ __launch_bounds__(512) void gemm_kernel(
        const __hip_bfloat16* __restrict__ Wb,
        const __hip_bfloat16* __restrict__ Xb,
        const float* __restrict__ bias,
        float* __restrict__ C)
{
    // [buf*2 + half][128 rows * 64 cols]
    __shared__ __align__(16) __hip_bfloat16 lsA[4][8192];   // 64 KiB
    __shared__ __align__(16) __hip_bfloat16 lsB[4][8192];   // 64 KiB

    const int tid  = threadIdx.x;
    const int lane = tid & 63;
    const int wid  = tid >> 6;    // 0..7 (divergent per compiler)
    const int swid = __builtin_amdgcn_readfirstlane(wid);   // wave-uniform SGPR
    const int wr   = wid >> 2;    // 0..1 (M)
    const int wc   = wid & 3;     // 0..3 (N)

    // XCD-aware bijective swizzle of the 256-block grid (16x16 tiles).
    const int bid = blockIdx.x;
    const int lin = (bid & 7) * 32 + (bid >> 3);
    const int bm  = (lin >> 4) << 8;
    const int bn  = (lin & 15) << 8;

    // --- staging addressing: scalar bases + ONE per-lane offset ---
    const int sr = lane >> 3;            // row within 8-row chunk
    const int lc = (lane & 7) ^ sr;      // logical 16B chunk to fetch (swizzle)
    const int loff = sr * K_DIM + lc * 8;                 // per-lane, 1 VGPR
    const size_t aoffu = (size_t)(bm + swid * 8) * K_DIM; // SGPR
    const size_t boffu = (size_t)(bn + swid * 8) * K_DIM; // SGPR
    int kst = 0;                                          // scalar k of staged tile

    // --- accumulators: per-wave 128x64 output, quadrants [m][n], frags [mi][ni]
    f32x4 acc[2][2][4][2];
#pragma unroll
    for (int m = 0; m < 2; ++m)
#pragma unroll
        for (int n = 0; n < 2; ++n)
#pragma unroll
            for (int mi = 0; mi < 4; ++mi)
#pragma unroll
                for (int ni = 0; ni < 2; ++ni) acc[m][n][mi][ni] = (f32x4)(0.0f);

    bf16x8 af[2][2][4];   // A frags [m-half][kk][mi]  (ping-pong by m)
    bf16x8 bf[2][2][2];   // B frags [n-half][kk][ni]

    const int fr = lane & 15;   // frag row
    const int fq = lane >> 4;   // quad
    const int fx = fr & 7;      // read-side swizzle xor

    const int e0 = (fq ^ fx) << 3;                      // kk=0 chunk, elements
    const int dK = (fx & 4) ? -32 : 32;                 // kk=1 chunk delta (elems)
    const __hip_bfloat16* aPtr[2];
    const __hip_bfloat16* bPtr[2];
    aPtr[0] = &lsA[0][0] + ((wr << 6) + fr) * 64 + e0;
    aPtr[1] = &lsA[1][0] + ((wr << 6) + fr) * 64 + e0;
    bPtr[0] = &lsB[0][0] + ((wc << 5) + fr) * 64 + e0;
    bPtr[1] = &lsB[1][0] + ((wc << 5) + fr) * 64 + e0;

// Stage A-half h of the tile at scalar k-offset kst into buffer p.
// Address = Wb + (bm + h*128 + (swid+8r)*8 + sr)*K_DIM + lc*8 + kst
//         = Wb + aoffu + h*(128*K_DIM) + r*(64*K_DIM) + kst + loff.
#define STAGE_A(h, p) do {                                                     \
    gload_lds16(Wb + aoffu + (h)*(128*K_DIM) + kst + loff,                     \
                &lsA[(p)*2 + (h)][swid << 9]);                                 \
    gload_lds16(Wb + aoffu + (h)*(128*K_DIM) + (64*K_DIM) + kst + loff,        \
                &lsA[(p)*2 + (h)][(swid + 8) << 9]);                           \
} while (0)

#define STAGE_B(h, p) do {                                                     \
    gload_lds16(Xb + boffu + (h)*(128*K_DIM) + kst + loff,                     \
                &lsB[(p)*2 + (h)][swid << 9]);                                 \
    gload_lds16(Xb + boffu + (h)*(128*K_DIM) + (64*K_DIM) + kst + loff,        \
                &lsB[(p)*2 + (h)][(swid + 8) << 9]);                           \
} while (0)

// 8 ds_read_b128: A-half h of buffer p -> af[h]
#define LOAD_AH(p, h) do {                                                     \
    const __hip_bfloat16* _pa = aPtr[h] + (p) * 16384;                         \
    af[h][0][0] = *(const bf16x8*)(const void*)(_pa);                          \
    af[h][0][1] = *(const bf16x8*)(const void*)(_pa + 1024);                   \
    af[h][0][2] = *(const bf16x8*)(const void*)(_pa + 2048);                   \
    af[h][0][3] = *(const bf16x8*)(const void*)(_pa + 3072);                   \
    af[h][1][0] = *(const bf16x8*)(const void*)(_pa + dK);                     \
    af[h][1][1] = *(const bf16x8*)(const void*)(_pa + dK + 1024);              \
    af[h][1][2] = *(const bf16x8*)(const void*)(_pa + dK + 2048);              \
    af[h][1][3] = *(const bf16x8*)(const void*)(_pa + dK + 3072);              \
} while (0)

// 4 ds_read_b128: B-half h of buffer p -> bf[h]
#define LOAD_BH(p, h) do {                                                     \
    const __hip_bfloat16* _pb = bPtr[h] + (p) * 16384;                         \
    bf[h][0][0] = *(const bf16x8*)(const void*)(_pb);                          \
    bf[h][0][1] = *(const bf16x8*)(const void*)(_pb + 1024);                   \
    bf[h][1][0] = *(const bf16x8*)(const void*)(_pb + dK);                     \
    bf[h][1][1] = *(const bf16x8*)(const void*)(_pb + dK + 1024);              \
} while (0)

#define MMA(m, n) do {                                                         \
    __builtin_amdgcn_s_setprio(1);                                             \
    _Pragma("unroll") for (int kk = 0; kk < 2; ++kk)                           \
    _Pragma("unroll") for (int mi = 0; mi < 4; ++mi)                           \
    _Pragma("unroll") for (int ni = 0; ni < 2; ++ni)                           \
        acc[m][n][mi][ni] = __builtin_amdgcn_mfma_f32_16x16x32_bf16(           \
            af[m][kk][mi], bf[n][kk][ni], acc[m][n][mi][ni], 0, 0, 0);         \
    __builtin_amdgcn_s_setprio(0);                                             \
} while (0)

#define BAR()        __builtin_amdgcn_s_barrier()
#define WAIT_LGKM(N) asm volatile("s_waitcnt lgkmcnt(" #N ")" ::: "memory")
#define WAIT_VM(N)   asm volatile("s_waitcnt vmcnt(" #N ")" ::: "memory")

    // STG: 1 = stage tile at kst into buffer p. VM: counted vmcnt at PH2-END
    // (drain-then-barrier-then-read invariant, R7). NRD: read-ahead of next
    // tile's A0,B0 (after the vm-drain barrier). LG3: lgkm count at ph3.
#define TILE(p, STG, VM, NRD, LG3) do {                                        \
    /* ph0 */                                                                  \
    LOAD_BH(p, 1);                                                             \
    WAIT_LGKM(4); MMA(0, 0); BAR();                                            \
    /* ph1 */                                                                  \
    LOAD_AH(p, 1);                                                             \
    if (STG) STAGE_A(0, p);                                                    \
    WAIT_LGKM(8); MMA(0, 1); BAR();                                            \
    /* ph2 */                                                                  \
    if (STG) { STAGE_B(0, p); STAGE_B(1, p); }                                 \
    WAIT_LGKM(0); MMA(1, 0);                                                   \
    VM;                                   /* drain BEFORE the barrier */       \
    BAR();                                                                     \
    /* ph3 */                                                                  \
    NRD;                                  /* safe: all waves drained */        \
    if (STG) STAGE_A(1, p);                                                    \
    LG3; MMA(1, 1); BAR();                                                     \
    if (STG) kst += 64;                                                        \
} while (0)

#define NRD0 do { LOAD_AH(1, 0); LOAD_BH(1, 0); } while (0)   /* next = buf1 */
#define NRD1 do { LOAD_AH(0, 0); LOAD_BH(0, 0); } while (0)   /* next = buf0 */

    // Prologue: stage tiles 0 (kst=0) and 1 (kst=64); drain on EVERY wave,
    // then barrier, THEN the initial read-ahead of tile0's A0,B0.
    STAGE_A(0, 0); STAGE_B(0, 0); STAGE_B(1, 0); STAGE_A(1, 0);
    kst = 64;
    STAGE_A(0, 1); STAGE_B(0, 1); STAGE_B(1, 1); STAGE_A(1, 1);
    kst = 128;
    WAIT_VM(8);
    BAR();
    LOAD_AH(0, 0); LOAD_BH(0, 0);

    // Main loop: tiles 0..61 (31 iterations x 2 tiles, steady vmcnt(6)).
    for (int it = 0; it < 31; ++it) {
        TILE(0, 1, WAIT_VM(6), NRD0, WAIT_LGKM(12));
        TILE(1, 1, WAIT_VM(6), NRD1, WAIT_LGKM(12));
    }
    // Tile 62: no staging; vmcnt(0) at ph2-end drains tile 63 before its
    // read-ahead.
    TILE(0, 0, WAIT_VM(0), NRD0, WAIT_LGKM(12));
    // Tile 63: pure compute, no read-ahead.
    TILE(1, 0, (void)0, (void)0, WAIT_LGKM(0));

#undef NRD1
#undef NRD0
#undef TILE
#undef WAIT_VM
#undef WAIT_LGKM
#undef BAR
#undef MMA
#undef LOAD_BH
#undef LOAD_AH
#undef STAGE_B
#undef STAGE_A

    // Epilogue: C/D layout col = lane&15, row = (lane>>4)*4 + reg.
#pragma unroll
    for (int n = 0; n < 2; ++n)
#pragma unroll
        for (int ni = 0; ni < 2; ++ni) {
            const int col = bn + n * 128 + (wc << 5) + (ni << 4) + fr;
            const float bv = bias[col];
#pragma unroll
            for (int m = 0; m < 2; ++m)
#pragma unroll
                for (int mi = 0; mi < 4; ++mi) {
                    const int r0 = bm + m * 128 + (wr << 6) + (mi << 4) + (fq << 2);
#pragma unroll
                    for (int i = 0; i < 4; ++i)
                        C[(size_t)(r0 + i) * K_DIM + col] = acc[m][n][mi][ni][i] + bv;
                }
        }
}

// ---------------------------------------------------------------------------
extern "C" void kernel_launch(void* const* d_in, const int* in_sizes, int n_in,
                              void* d_out, int out_size, void* d_ws, size_t ws_size,
                              hipStream_t stream)
{
    (void)in_sizes; (void)n_in; (void)out_size; (void)ws_size;

    const float* x    = (const float*)d_in[0];
    KronPtrs P;
    for (int i = 0; i < 8; ++i) {
        P.a[i] = (const float*)d_in[1 + i];
        P.b[i] = (const float*)d_in[9 + i];
    }
    const float* bias = (const float*)d_in[17];

    __hip_bfloat16* Wb = (__hip_bfloat16*)d_ws;                               // 32 MiB
    __hip_bfloat16* Xb = (__hip_bfloat16*)((char*)d_ws +
                          (size_t)K_DIM * K_DIM * sizeof(__hip_bfloat16));    // 32 MiB
    float* y = (float*)d_out;

    prologue_kernel<<<12288, 256, 0, stream>>>(P, x, Wb, Xb);

    gemm_kernel<<<256, 512, 0, stream>>>(Wb, Xb, bias, y);
}